// Round 2
// baseline (323.641 us; speedup 1.0000x reference)
//
#include <hip/hip_runtime.h>

// GaussianVoxel fused single-kernel writer.
// Output: 4 levels [16,17,zr,64,64] f32, zr in {1,2,4,64}, concatenated flat.
// Z_COEFFS=(1,1,1,13): g0..g2 are [1,13,13], g3 is [13,13,13]; PATCH=13, PAD=6.
// 316 MB of mostly zeros -> pure write-bandwidth problem. One block per 64x64
// z-slice; fast path = zero-fill (no per-element checks) when the slice's z
// doesn't intersect the (b,j) patch; slow path = predicated gather from g.
//
// Slice counts per level: 272, 544, 1088, 17408 (total 19312).
// Flat output base offsets: 0, 1114112, 3342336, 7798784 (elements).

#define PAD 6
#define PATCH 13
#define PP 169        // 13*13

__global__ __launch_bounds__(256)
void GaussianVoxel_fused(const float* __restrict__ coords,
                         const float* __restrict__ g0,
                         const float* __restrict__ g1,
                         const float* __restrict__ g2,
                         const float* __restrict__ g3,
                         float* __restrict__ out) {
    const int s = blockIdx.x;              // global slice id, 0..19311

    // Decode (level, bj, z) — all wave-uniform.
    int base, zsh;                         // zsh = log2(z_res)
    long long obase;                       // element offset of this level
    const float* g;
    if (s < 272)       { base = 0;    zsh = 0; obase = 0LL;       g = g0; }
    else if (s < 816)  { base = 272;  zsh = 1; obase = 1114112LL; g = g1; }
    else if (s < 1904) { base = 816;  zsh = 2; obase = 3342336LL; g = g2; }
    else               { base = 1904; zsh = 6; obase = 7798784LL; g = g3; }
    const int sid = s - base;
    const int bj  = sid >> zsh;
    const int z   = sid & ((1 << zsh) - 1);
    const int zc   = (zsh == 6) ? 13 : 1;
    const int zpad = (zsh == 6) ? 6  : 0;

    float4* __restrict__ o4 = (float4*)(out + obase + (long long)sid * 4096);

    // Per-(b,j) integer coords.
    const int xi = (int)coords[bj * 3 + 0];
    const int yi = (int)coords[bj * 3 + 1];
    const int zi = (int)coords[bj * 3 + 2];

    // zidx = ceil(zi * zr / 64) - 1  (exact integer form; zi in [0,63])
    const int zidx = (((zi << zsh) + 63) >> 6) - 1;
    const int gz = z - zidx + zpad;        // patch z-coordinate of this slice

    const float4 zero = make_float4(0.f, 0.f, 0.f, 0.f);

    if ((unsigned)gz >= (unsigned)zc) {
        // Fast path: slice entirely zero. 4 coalesced float4 stores/thread.
        #pragma unroll
        for (int i = 0; i < 4; ++i)
            o4[i * 256 + threadIdx.x] = zero;
        return;
    }

    // Slow path: slice intersects the patch in z. Predicated gather.
    const float* __restrict__ gsl = g + gz * PP;   // 13x13 plane (gz==0 for L0-2)
    #pragma unroll
    for (int i = 0; i < 4; ++i) {
        const int f4 = i * 256 + threadIdx.x;      // float4 index in slice
        const int e  = f4 << 2;                    // element index (one row: 64%4==0)
        const int y  = e >> 6;
        const int x  = e & 63;
        const int gy = y - yi + PAD;
        float4 v = zero;
        if ((unsigned)gy < (unsigned)PATCH) {
            const float* row = gsl + gy * PATCH;
            #pragma unroll
            for (int k = 0; k < 4; ++k) {
                const int gx = x + k - xi + PAD;
                if ((unsigned)gx < (unsigned)PATCH)
                    ((float*)&v)[k] = row[gx];
            }
        }
        o4[f4] = v;
    }
}

extern "C" void kernel_launch(void* const* d_in, const int* in_sizes, int n_in,
                              void* d_out, int out_size, void* d_ws, size_t ws_size,
                              hipStream_t stream) {
    const float* coords = (const float*)d_in[0];
    const float* g0     = (const float*)d_in[1];
    const float* g1     = (const float*)d_in[2];
    const float* g2     = (const float*)d_in[3];
    const float* g3     = (const float*)d_in[4];
    float* out = (float*)d_out;

    // One block per 64x64 slice: 272*(1+2+4+64) = 19312 slices.
    GaussianVoxel_fused<<<19312, 256, 0, stream>>>(coords, g0, g1, g2, g3, out);
}

// Round 5
// 318.812 us; speedup vs baseline: 1.0151x; 1.0151x over previous
//
#include <hip/hip_runtime.h>

// GaussianVoxel fused single-kernel writer, nontemporal-store variant.
// Output: 4 levels [16,17,zr,64,64] f32, zr in {1,2,4,64}, concatenated flat.
// Z_COEFFS=(1,1,1,13): g0..g2 are [1,13,13], g3 is [13,13,13]; PATCH=13, PAD=6.
// 316 MB of mostly zeros -> pure write-bandwidth problem. One block per 64x64
// z-slice; fast path = zero-fill when the slice's z doesn't intersect the
// (b,j) patch; slow path = predicated gather from g. All stores nontemporal
// (316 MB >> 32 MB L2 — no reuse, stream past L2).
//
// NOTE: __builtin_nontemporal_store needs a clang vector type, not HIP's
// float4 class — use ext_vector_type(4).
//
// Timing note (R2 post-mortem): dur_us includes ~211 us of harness 0xAA poison
// fill (1.266 GB) + ~50 us fixed overhead; our controllable part is the 316 MB
// write (floor ~50 us @ 6.3 TB/s).

#define PAD 6
#define PATCH 13
#define PP 169        // 13*13

typedef float f32x4 __attribute__((ext_vector_type(4)));

__global__ __launch_bounds__(256)
void GaussianVoxel_fused(const float* __restrict__ coords,
                         const float* __restrict__ g0,
                         const float* __restrict__ g1,
                         const float* __restrict__ g2,
                         const float* __restrict__ g3,
                         float* __restrict__ out) {
    const int s = blockIdx.x;              // global slice id, 0..19311

    // Decode (level, bj, z) — all wave-uniform.
    int base, zsh;                         // zsh = log2(z_res)
    long long obase;                       // element offset of this level
    const float* g;
    if (s < 272)       { base = 0;    zsh = 0; obase = 0LL;       g = g0; }
    else if (s < 816)  { base = 272;  zsh = 1; obase = 1114112LL; g = g1; }
    else if (s < 1904) { base = 816;  zsh = 2; obase = 3342336LL; g = g2; }
    else               { base = 1904; zsh = 6; obase = 7798784LL; g = g3; }
    const int sid = s - base;
    const int bj  = sid >> zsh;
    const int z   = sid & ((1 << zsh) - 1);
    const int zc   = (zsh == 6) ? 13 : 1;
    const int zpad = (zsh == 6) ? 6  : 0;

    f32x4* __restrict__ o4 = (f32x4*)(out + obase + (long long)sid * 4096);

    // Per-(b,j) integer coords.
    const int xi = (int)coords[bj * 3 + 0];
    const int yi = (int)coords[bj * 3 + 1];
    const int zi = (int)coords[bj * 3 + 2];

    // zidx = ceil(zi * zr / 64) - 1  (exact integer form; zi in [0,63])
    const int zidx = (((zi << zsh) + 63) >> 6) - 1;
    const int gz = z - zidx + zpad;        // patch z-coordinate of this slice

    const f32x4 zero = {0.f, 0.f, 0.f, 0.f};

    if ((unsigned)gz >= (unsigned)zc) {
        // Fast path: slice entirely zero. 4 coalesced nontemporal 16B stores/thread.
        #pragma unroll
        for (int i = 0; i < 4; ++i)
            __builtin_nontemporal_store(zero, &o4[i * 256 + threadIdx.x]);
        return;
    }

    // Slow path: slice intersects the patch in z. Predicated gather.
    const float* __restrict__ gsl = g + gz * PP;   // 13x13 plane (gz==0 for L0-2)
    #pragma unroll
    for (int i = 0; i < 4; ++i) {
        const int f4 = i * 256 + threadIdx.x;      // float4 index in slice
        const int e  = f4 << 2;                    // element index (one row: 64%4==0)
        const int y  = e >> 6;
        const int x  = e & 63;
        const int gy = y - yi + PAD;
        f32x4 v = zero;
        if ((unsigned)gy < (unsigned)PATCH) {
            const float* row = gsl + gy * PATCH;
            #pragma unroll
            for (int k = 0; k < 4; ++k) {
                const int gx = x + k - xi + PAD;
                if ((unsigned)gx < (unsigned)PATCH)
                    v[k] = row[gx];
            }
        }
        __builtin_nontemporal_store(v, &o4[f4]);
    }
}

extern "C" void kernel_launch(void* const* d_in, const int* in_sizes, int n_in,
                              void* d_out, int out_size, void* d_ws, size_t ws_size,
                              hipStream_t stream) {
    const float* coords = (const float*)d_in[0];
    const float* g0     = (const float*)d_in[1];
    const float* g1     = (const float*)d_in[2];
    const float* g2     = (const float*)d_in[3];
    const float* g3     = (const float*)d_in[4];
    float* out = (float*)d_out;

    // One block per 64x64 slice: 272*(1+2+4+64) = 19312 slices.
    GaussianVoxel_fused<<<19312, 256, 0, stream>>>(coords, g0, g1, g2, g3, out);
}